// Round 14
// baseline (469.866 us; speedup 1.0000x reference)
//
#include <hip/hip_runtime.h>
#include <hip/hip_bf16.h>
#include <stdint.h>

#define BDIM 8192
#define HDIM 2048
#define KDIM 4096   // IN + H
#define NDIM 6144   // 3 * H

using f32x4  = __attribute__((ext_vector_type(4))) float;
using bf16x8 = __attribute__((ext_vector_type(8))) short;
using short8 = __attribute__((ext_vector_type(8))) short;

__device__ __forceinline__ uint16_t f2bf(float f) {
    union { float f; uint32_t u; } v;
    v.f = f;
    uint32_t r = v.u + 0x7fffu + ((v.u >> 16) & 1u);  // RNE
    return (uint16_t)(r >> 16);
}

__device__ __forceinline__ float bf2f(uint16_t u) {
    union { uint32_t u; float f; } v;
    v.u = ((uint32_t)u) << 16;
    return v.f;
}

__device__ __forceinline__ float fast_sigmoid(float x) {
    return 1.0f / (1.0f + __expf(-x));
}

__device__ __forceinline__ float fast_tanh(float x) {
    float ax = fabsf(x);
    float t = __expf(-2.0f * ax);
    float r = (1.0f - t) / (1.0f + t);
    return copysignf(r, x);
}

__device__ __forceinline__ short8 cvt8(f32x4 a, f32x4 b) {
    short8 o;
    o[0] = (short)f2bf(a[0]); o[1] = (short)f2bf(a[1]);
    o[2] = (short)f2bf(a[2]); o[3] = (short)f2bf(a[3]);
    o[4] = (short)f2bf(b[0]); o[5] = (short)f2bf(b[1]);
    o[6] = (short)f2bf(b[2]); o[7] = (short)f2bf(b[3]);
    return o;
}

// ---------------- fused conversion kernel (8 elems/thread/iter) ----------
// xh = concat(x,h) -> bf16 [8192][4096]; Wb = [W_f;W_o;W_c] -> bf16 [6144][4096]
#define XH_CH8 ((int64_t)BDIM * KDIM / 8)
#define W_CH8  ((int64_t)3 * HDIM * KDIM / 8)
#define PER_GATE ((int64_t)HDIM * KDIM)

__global__ void cvt_all_kernel(const float* __restrict__ x,
                               const float* __restrict__ h,
                               const float* __restrict__ Wf,
                               const float* __restrict__ Wo,
                               const float* __restrict__ Wc,
                               uint16_t* __restrict__ xh,
                               uint16_t* __restrict__ Wb) {
    const int64_t total = XH_CH8 + W_CH8;
    for (int64_t i = (int64_t)blockIdx.x * blockDim.x + threadIdx.x; i < total;
         i += (int64_t)gridDim.x * blockDim.x) {
        const float* src;
        uint16_t* dst;
        if (i < XH_CH8) {
            int64_t e = i << 3;
            int b = (int)(e >> 12);
            int k = (int)(e & 4095);
            src = (k < 2048) ? (x + (int64_t)b * 2048 + k)
                             : (h + (int64_t)b * 2048 + (k - 2048));
            dst = xh + e;
        } else {
            int64_t e = (i - XH_CH8) << 3;
            // gate select without 64-bit division
            int gate = (e >= 2 * PER_GATE) ? 2 : (e >= PER_GATE ? 1 : 0);
            int64_t rem = e - (int64_t)gate * PER_GATE;
            const float* w = (gate == 0) ? Wf : (gate == 1) ? Wo : Wc;
            src = w + rem;
            dst = Wb + e;
        }
        f32x4 v0 = *(const f32x4*)(src);
        f32x4 v1 = *(const f32x4*)(src + 4);
        *(short8*)dst = cvt8(v0, v1);
    }
}

// ---------------- 256x256 4-phase GEMM (mb-major cohort swizzle) ---------
// Structure = round-13 gemm4p; ONLY the l->(mb,nb) decomposition changed.
// Round-13 (nb-major): each XCD's A-band re-streamed every round (~3x64 MB
// of A fetch; FETCH 299 MB). New (mb-major):
//   x = bid & 7 (XCD), l = bid >> 3 in [0,96)
//   mb = x*4 + l/24   (one mb panel per 24 consecutive l)
//   nb = l % 24
// A concurrent round (32 blocks/XCD at 1 block/CU) spans 1-2 mb panels
// (2-4 MiB -> L2-resident on that XCD); A fetched ~once (64 MB). W (48 MiB)
// streams via L3 (resident across rounds). B-stage loads hit L3 (~400 cyc,
// inside WC8 slack) instead of HBM (~900 cyc).

#define STAGE_A(slot, t, h) do { \
    _Pragma("unroll") for (int q_ = 0; q_ < 2; ++q_) { \
        const int r_ = s_row[q_]; \
        const uint16_t* src_ = A + (int64_t)(m0 + ((r_ >> 6) << 7) + ((h) << 6) + (r_ & 63)) * KDIM + ((t) << 6) + s_kc[q_]; \
        __builtin_amdgcn_global_load_lds((__attribute__((address_space(1))) void*)(src_), \
            (__attribute__((address_space(3))) void*)(&lds[slot][(q_ * 512 + tid) * 8]), 16, 0, 0); \
    } } while (0)

#define STAGE_B(slot, t, h) do { \
    _Pragma("unroll") for (int q_ = 0; q_ < 2; ++q_) { \
        const int r_ = s_row[q_]; \
        const uint16_t* src_ = Wb + (int64_t)(n0 + ((r_ >> 5) << 6) + ((h) << 5) + (r_ & 31)) * KDIM + ((t) << 6) + s_kc[q_]; \
        __builtin_amdgcn_global_load_lds((__attribute__((address_space(1))) void*)(src_), \
            (__attribute__((address_space(3))) void*)(&lds[slot][(q_ * 512 + tid) * 8]), 16, 0, 0); \
    } } while (0)

// read logical (slot, srow, kchunk) with swizzle
#define RD(slot, srow, kc) \
    (*(const bf16x8*)((const char*)(&lds[0][0]) + ((slot) * 16384) + ((srow) * 128) + ((((kc) ^ ((srow) & 7))) * 16)))

#define RD_A(tp, h) do { \
    _Pragma("unroll") for (int kk = 0; kk < 2; ++kk) \
        _Pragma("unroll") for (int mf = 0; mf < 4; ++mf) \
            aF[kk][mf] = RD((((tp) & 1) << 1) + (h), wm * 64 + mf * 16 + fr, kk * 4 + kg); \
} while (0)

#define RD_B(dst, tp, h) do { \
    _Pragma("unroll") for (int kk = 0; kk < 2; ++kk) \
        _Pragma("unroll") for (int nf = 0; nf < 2; ++nf) \
            dst[kk][nf] = RD(4 + (((tp) & 1) << 1) + (h), wn * 32 + nf * 16 + fr, kk * 4 + kg); \
} while (0)

#define MM(qm, qn, bsrc) do { \
    _Pragma("unroll") for (int kk = 0; kk < 2; ++kk) \
        _Pragma("unroll") for (int mf = 0; mf < 4; ++mf) \
            _Pragma("unroll") for (int nf = 0; nf < 2; ++nf) \
                acc[(qm) * 4 + mf][(qn) * 2 + nf] = __builtin_amdgcn_mfma_f32_16x16x32_bf16( \
                    aF[kk][mf], bsrc[kk][nf], acc[(qm) * 4 + mf][(qn) * 2 + nf], 0, 0, 0); \
} while (0)

#define PH4(READS1, STAGE, MM1, READS2, MM2, WAITC) do { \
    asm volatile("" ::: "memory"); \
    READS1; \
    STAGE; \
    asm volatile("" ::: "memory"); \
    __builtin_amdgcn_s_setprio(1); \
    MM1; \
    __builtin_amdgcn_s_setprio(0); \
    asm volatile("" ::: "memory"); \
    READS2; \
    asm volatile("" ::: "memory"); \
    __builtin_amdgcn_s_setprio(1); \
    MM2; \
    __builtin_amdgcn_s_setprio(0); \
    WAITC; \
    __builtin_amdgcn_s_barrier(); \
} while (0)

#define WC8 asm volatile("s_waitcnt vmcnt(8)" ::: "memory")
#define WC6 asm volatile("s_waitcnt vmcnt(6)" ::: "memory")
#define WC2 asm volatile("s_waitcnt vmcnt(2)" ::: "memory")
#define WC0 asm volatile("s_waitcnt vmcnt(0)" ::: "memory")

__global__ __launch_bounds__(512, 2) void lstm_gemm4p_kernel(
    const uint16_t* __restrict__ A,
    const uint16_t* __restrict__ Wb,
    uint16_t* __restrict__ G) {
    __shared__ uint16_t lds[8][8192];  // 128 KiB

    const int tid = threadIdx.x;
    const int lane = tid & 63;
    const int kg = lane >> 4;
    const int fr = lane & 15;
    const int wid = tid >> 6;
    const int wm = wid >> 2;   // 0..1
    const int wn = wid & 3;    // 0..3

    // mb-major cohort swizzle (bijective: 8 XCD x 4 mb x 24 nb)
    const int bid = blockIdx.x;
    const int xcd = bid & 7;
    const int l = bid >> 3;            // 0..95
    const int mb = xcd * 4 + l / 24;   // 0..31
    const int nb = l - (l / 24) * 24;  // 0..23
    const int m0 = mb << 8;
    const int n0 = nb << 8;

    // staging constants: chunk = q*512 + tid -> row, swizzled k-chunk
    int s_row[2], s_kc[2];
#pragma unroll
    for (int q_ = 0; q_ < 2; ++q_) {
        const int chunk = q_ * 512 + tid;
        const int r_ = chunk >> 3;
        const int c_ = chunk & 7;
        s_row[q_] = r_;
        s_kc[q_] = (c_ ^ (r_ & 7)) * 8;  // element offset
    }

    f32x4 acc[8][4] = {};
    bf16x8 aF[2][4];
    bf16x8 bF0[2][2];
    bf16x8 bF1[2][2];

    // prologue (14 loads, FIFO oldest->newest):
    // s4(2),s0(2),s5(2),s1(2),s6(2),s2(2),s7(2)
    STAGE_B(4, 0, 0); STAGE_A(0, 0, 0); STAGE_B(5, 0, 1);
    STAGE_A(1, 0, 1); STAGE_B(6, 1, 0);
    STAGE_A(2, 1, 0); STAGE_B(7, 1, 1);
    WC8;  // completes s4,s0,s5 (loads 1-6); leaves {s1,s6,s2,s7} = invariant
    __builtin_amdgcn_s_barrier();
    RD_B(bF0, 0, 0);  // pre-read B(0,h0) from s4 (complete)
    asm volatile("s_waitcnt lgkmcnt(0)" ::: "memory");
    __builtin_amdgcn_s_barrier();  // s4 safe to re-stage from Q1 on

    // 64 K-tiles, 2 per iteration; i=31 is the peeled tail
    for (int i = 0; i < 31; ++i) {
        const int t0 = 2 * i;
        const int t1 = t0 + 1, t2 = t0 + 2, t3 = t0 + 3;
        PH4(RD_A(t0, 0); RD_B(bF1, t0, 1),
            STAGE_A(3, t1, 1); STAGE_B(4, t2, 0),
            MM(0, 0, bF0); MM(0, 1, bF1), ;, ;, WC8);
        PH4(RD_A(t0, 1),
            STAGE_A(0, t2, 0); STAGE_B(5, t2, 1),
            MM(1, 0, bF0), RD_B(bF0, t1, 0), MM(1, 1, bF1), WC8);
        PH4(RD_A(t1, 0); RD_B(bF1, t1, 1),
            STAGE_A(1, t2, 1); STAGE_B(6, t3, 0),
            MM(0, 0, bF0); MM(0, 1, bF1), ;, ;, WC8);
        PH4(RD_A(t1, 1),
            STAGE_A(2, t3, 0); STAGE_B(7, t3, 1),
            MM(1, 0, bF0), RD_B(bF0, t2, 0), MM(1, 1, bF1), WC8);
    }
    // tail: t0=62, t1=63. Entering outstanding = {s1,s6(Q3), s2,s7(Q4)} = 8.
    // T1 rd s0,s5 (completed by loop Q4 WC8); stage s3 (+2 -> 10);
    //    WC6 completes s1,s6 (for T2); leaves {s2,s7,s3}.
    // T2 rd s1,s6; WC2 completes s2,s7 (for T3); leaves {s3}.
    // T3 rd s2,s7; WC0 completes s3 (for T4).
    // T4 rd s3.
    PH4(RD_A(62, 0); RD_B(bF1, 62, 1),
        STAGE_A(3, 63, 1),
        MM(0, 0, bF0); MM(0, 1, bF1), ;, ;, WC6);
    PH4(RD_A(62, 1), ;,
        MM(1, 0, bF0), RD_B(bF0, 63, 0), MM(1, 1, bF1), WC2);
    PH4(RD_A(63, 0); RD_B(bF1, 63, 1), ;,
        MM(0, 0, bF0); MM(0, 1, bF1), ;, ;, WC0);
    PH4(RD_A(63, 1), ;,
        MM(1, 0, bF0), ;, MM(1, 1, bF1), );

    // C-write: D layout col = lane&15, row = (lane>>4)*4 + j
#pragma unroll
    for (int mf = 0; mf < 8; ++mf) {
#pragma unroll
        for (int nf = 0; nf < 4; ++nf) {
            const int n = n0 + wn * 64 + nf * 16 + fr;
            const int64_t mbase = (int64_t)(m0 + wm * 128 + mf * 16 + kg * 4);
#pragma unroll
            for (int j = 0; j < 4; ++j) {
                G[(mbase + j) * NDIM + n] = f2bf(acc[mf][nf][j]);
            }
        }
    }
}

// ---------------- LSTM elementwise epilogue (plain vectorized I/O) -------

__global__ void lstm_epi_kernel(const uint16_t* __restrict__ G,
                                const float* __restrict__ c_prev,
                                const float* __restrict__ b_f,
                                const float* __restrict__ b_o,
                                const float* __restrict__ b_c,
                                float* __restrict__ h_out,
                                float* __restrict__ c_out) {
    const int64_t total = (int64_t)BDIM * HDIM / 8;
    for (int64_t i = (int64_t)blockIdx.x * blockDim.x + threadIdx.x; i < total;
         i += (int64_t)gridDim.x * blockDim.x) {
        const int64_t e = i << 3;
        const int m = (int)(e >> 11);
        const int n = (int)(e & 2047);
        const int64_t gb = (int64_t)m * NDIM + n;
        const short8 fv = *(const short8*)(G + gb);
        const short8 ov = *(const short8*)(G + gb + HDIM);
        const short8 cv = *(const short8*)(G + gb + 2 * HDIM);
        const f32x4 cp0 = *(const f32x4*)(c_prev + (int64_t)m * HDIM + n);
        const f32x4 cp1 = *(const f32x4*)(c_prev + (int64_t)m * HDIM + n + 4);
        float cp[8] = {cp0[0], cp0[1], cp0[2], cp0[3], cp1[0], cp1[1], cp1[2], cp1[3]};
        float hr[8], cr[8];
#pragma unroll
        for (int j = 0; j < 8; ++j) {
            const float fpre = bf2f((uint16_t)fv[j]) + b_f[n + j];
            const float opre = bf2f((uint16_t)ov[j]) + b_o[n + j];
            const float cpre = bf2f((uint16_t)cv[j]) + b_c[n + j];
            const float ft = fast_sigmoid(fpre);
            const float ot = fast_sigmoid(opre);
            const float ch = fast_tanh(cpre);
            const float ct = ft * cp[j] + (1.0f - ft) * ch;
            hr[j] = ot * fast_tanh(ct);
            cr[j] = ct;
        }
        f32x4 h0 = {hr[0], hr[1], hr[2], hr[3]};
        f32x4 h1 = {hr[4], hr[5], hr[6], hr[7]};
        f32x4 c0 = {cr[0], cr[1], cr[2], cr[3]};
        f32x4 c1 = {cr[4], cr[5], cr[6], cr[7]};
        *(f32x4*)(h_out + (int64_t)m * HDIM + n) = h0;
        *(f32x4*)(h_out + (int64_t)m * HDIM + n + 4) = h1;
        *(f32x4*)(c_out + (int64_t)m * HDIM + n) = c0;
        *(f32x4*)(c_out + (int64_t)m * HDIM + n + 4) = c1;
    }
}

extern "C" void kernel_launch(void* const* d_in, const int* in_sizes, int n_in,
                              void* d_out, int out_size, void* d_ws, size_t ws_size,
                              hipStream_t stream) {
    const float* x_t   = (const float*)d_in[0];
    const float* h_t_1 = (const float*)d_in[1];
    const float* c_t_1 = (const float*)d_in[2];
    const float* W_f   = (const float*)d_in[3];
    const float* b_f   = (const float*)d_in[4];
    const float* W_o   = (const float*)d_in[5];
    const float* b_o   = (const float*)d_in[6];
    const float* W_c   = (const float*)d_in[7];
    const float* b_c   = (const float*)d_in[8];

    uint16_t* xh  = (uint16_t*)d_ws;                            // 64 MiB
    uint16_t* Wbf = xh + (size_t)BDIM * KDIM;                   // 48 MiB
    uint16_t* G   = Wbf + (size_t)NDIM * KDIM;                  // 96 MiB

    float* h_out = (float*)d_out;
    float* c_out = h_out + (size_t)BDIM * HDIM;

    cvt_all_kernel<<<2048, 256, 0, stream>>>(x_t, h_t_1, W_f, W_o, W_c, xh, Wbf);
    lstm_gemm4p_kernel<<<768, 512, 0, stream>>>(xh, Wbf, G);
    lstm_epi_kernel<<<2048, 256, 0, stream>>>(G, c_t_1, b_f, b_o, b_c,
                                              h_out, c_out);
}

// Round 15
// 441.778 us; speedup vs baseline: 1.0636x; 1.0636x over previous
//
#include <hip/hip_runtime.h>
#include <hip/hip_bf16.h>
#include <stdint.h>

#define BDIM 8192
#define HDIM 2048
#define KDIM 4096   // IN + H
#define NDIM 6144   // 3 * H

using f32x4  = __attribute__((ext_vector_type(4))) float;
using bf16x8 = __attribute__((ext_vector_type(8))) short;
using short8 = __attribute__((ext_vector_type(8))) short;

__device__ __forceinline__ uint16_t f2bf(float f) {
    union { float f; uint32_t u; } v;
    v.f = f;
    uint32_t r = v.u + 0x7fffu + ((v.u >> 16) & 1u);  // RNE
    return (uint16_t)(r >> 16);
}

__device__ __forceinline__ float bf2f(uint16_t u) {
    union { uint32_t u; float f; } v;
    v.u = ((uint32_t)u) << 16;
    return v.f;
}

__device__ __forceinline__ float fast_sigmoid(float x) {
    return 1.0f / (1.0f + __expf(-x));
}

__device__ __forceinline__ float fast_tanh(float x) {
    float ax = fabsf(x);
    float t = __expf(-2.0f * ax);
    float r = (1.0f - t) / (1.0f + t);
    return copysignf(r, x);
}

__device__ __forceinline__ short8 cvt8(f32x4 a, f32x4 b) {
    short8 o;
    o[0] = (short)f2bf(a[0]); o[1] = (short)f2bf(a[1]);
    o[2] = (short)f2bf(a[2]); o[3] = (short)f2bf(a[3]);
    o[4] = (short)f2bf(b[0]); o[5] = (short)f2bf(b[1]);
    o[6] = (short)f2bf(b[2]); o[7] = (short)f2bf(b[3]);
    return o;
}

// ---------------- fused conversion kernel (8 elems/thread/iter) ----------
// xh = concat(x,h) -> bf16 [8192][4096]; Wb = [W_f;W_o;W_c] -> bf16 [6144][4096]
#define XH_CH8 ((int64_t)BDIM * KDIM / 8)
#define W_CH8  ((int64_t)3 * HDIM * KDIM / 8)
#define PER_GATE ((int64_t)HDIM * KDIM)

__global__ void cvt_all_kernel(const float* __restrict__ x,
                               const float* __restrict__ h,
                               const float* __restrict__ Wf,
                               const float* __restrict__ Wo,
                               const float* __restrict__ Wc,
                               uint16_t* __restrict__ xh,
                               uint16_t* __restrict__ Wb) {
    const int64_t total = XH_CH8 + W_CH8;
    for (int64_t i = (int64_t)blockIdx.x * blockDim.x + threadIdx.x; i < total;
         i += (int64_t)gridDim.x * blockDim.x) {
        const float* src;
        uint16_t* dst;
        if (i < XH_CH8) {
            int64_t e = i << 3;
            int b = (int)(e >> 12);
            int k = (int)(e & 4095);
            src = (k < 2048) ? (x + (int64_t)b * 2048 + k)
                             : (h + (int64_t)b * 2048 + (k - 2048));
            dst = xh + e;
        } else {
            int64_t e = (i - XH_CH8) << 3;
            // gate select without 64-bit division
            int gate = (e >= 2 * PER_GATE) ? 2 : (e >= PER_GATE ? 1 : 0);
            int64_t rem = e - (int64_t)gate * PER_GATE;
            const float* w = (gate == 0) ? Wf : (gate == 1) ? Wo : Wc;
            src = w + rem;
            dst = Wb + e;
        }
        f32x4 v0 = *(const f32x4*)(src);
        f32x4 v1 = *(const f32x4*)(src + 4);
        *(short8*)dst = cvt8(v0, v1);
    }
}

// ---------------- 256x256 4-phase GEMM (cohort-localized swizzle) --------
// Round-13 kernel verbatim — best measured: total 441.2 us, FETCH 299 MB,
// MfmaUtil 62.3%. (Round-14's mb-major variant regressed: FETCH 700+,
// MfmaUtil 57-59% — nb-sliced working set is the winning property.)
// Bijective map (768 = 8 XCD x 96):
//   x = bid & 7 (XCD), l = bid >> 3 in [0,96)
//   mb = x*4 + ((l>>3)&3)        (4-mb band per XCD)
//   nb = ((l>>5)<<3) + (l&7)     (8-nb slice per 32-block phase)
// Cohort working set: A 64 MiB + W-slice 16 MiB = 80 MiB << 256 MiB L3;
// re-reads become cache hits (~200-400 cyc << WC8 slack).

#define STAGE_A(slot, t, h) do { \
    _Pragma("unroll") for (int q_ = 0; q_ < 2; ++q_) { \
        const int r_ = s_row[q_]; \
        const uint16_t* src_ = A + (int64_t)(m0 + ((r_ >> 6) << 7) + ((h) << 6) + (r_ & 63)) * KDIM + ((t) << 6) + s_kc[q_]; \
        __builtin_amdgcn_global_load_lds((__attribute__((address_space(1))) void*)(src_), \
            (__attribute__((address_space(3))) void*)(&lds[slot][(q_ * 512 + tid) * 8]), 16, 0, 0); \
    } } while (0)

#define STAGE_B(slot, t, h) do { \
    _Pragma("unroll") for (int q_ = 0; q_ < 2; ++q_) { \
        const int r_ = s_row[q_]; \
        const uint16_t* src_ = Wb + (int64_t)(n0 + ((r_ >> 5) << 6) + ((h) << 5) + (r_ & 31)) * KDIM + ((t) << 6) + s_kc[q_]; \
        __builtin_amdgcn_global_load_lds((__attribute__((address_space(1))) void*)(src_), \
            (__attribute__((address_space(3))) void*)(&lds[slot][(q_ * 512 + tid) * 8]), 16, 0, 0); \
    } } while (0)

// read logical (slot, srow, kchunk) with swizzle
#define RD(slot, srow, kc) \
    (*(const bf16x8*)((const char*)(&lds[0][0]) + ((slot) * 16384) + ((srow) * 128) + ((((kc) ^ ((srow) & 7))) * 16)))

#define RD_A(tp, h) do { \
    _Pragma("unroll") for (int kk = 0; kk < 2; ++kk) \
        _Pragma("unroll") for (int mf = 0; mf < 4; ++mf) \
            aF[kk][mf] = RD((((tp) & 1) << 1) + (h), wm * 64 + mf * 16 + fr, kk * 4 + kg); \
} while (0)

#define RD_B(dst, tp, h) do { \
    _Pragma("unroll") for (int kk = 0; kk < 2; ++kk) \
        _Pragma("unroll") for (int nf = 0; nf < 2; ++nf) \
            dst[kk][nf] = RD(4 + (((tp) & 1) << 1) + (h), wn * 32 + nf * 16 + fr, kk * 4 + kg); \
} while (0)

#define MM(qm, qn, bsrc) do { \
    _Pragma("unroll") for (int kk = 0; kk < 2; ++kk) \
        _Pragma("unroll") for (int mf = 0; mf < 4; ++mf) \
            _Pragma("unroll") for (int nf = 0; nf < 2; ++nf) \
                acc[(qm) * 4 + mf][(qn) * 2 + nf] = __builtin_amdgcn_mfma_f32_16x16x32_bf16( \
                    aF[kk][mf], bsrc[kk][nf], acc[(qm) * 4 + mf][(qn) * 2 + nf], 0, 0, 0); \
} while (0)

#define PH4(READS1, STAGE, MM1, READS2, MM2, WAITC) do { \
    asm volatile("" ::: "memory"); \
    READS1; \
    STAGE; \
    asm volatile("" ::: "memory"); \
    __builtin_amdgcn_s_setprio(1); \
    MM1; \
    __builtin_amdgcn_s_setprio(0); \
    asm volatile("" ::: "memory"); \
    READS2; \
    asm volatile("" ::: "memory"); \
    __builtin_amdgcn_s_setprio(1); \
    MM2; \
    __builtin_amdgcn_s_setprio(0); \
    WAITC; \
    __builtin_amdgcn_s_barrier(); \
} while (0)

#define WC8 asm volatile("s_waitcnt vmcnt(8)" ::: "memory")
#define WC6 asm volatile("s_waitcnt vmcnt(6)" ::: "memory")
#define WC2 asm volatile("s_waitcnt vmcnt(2)" ::: "memory")
#define WC0 asm volatile("s_waitcnt vmcnt(0)" ::: "memory")

__global__ __launch_bounds__(512, 2) void lstm_gemm4p_kernel(
    const uint16_t* __restrict__ A,
    const uint16_t* __restrict__ Wb,
    uint16_t* __restrict__ G) {
    __shared__ uint16_t lds[8][8192];  // 128 KiB

    const int tid = threadIdx.x;
    const int lane = tid & 63;
    const int kg = lane >> 4;
    const int fr = lane & 15;
    const int wid = tid >> 6;
    const int wm = wid >> 2;   // 0..1
    const int wn = wid & 3;    // 0..3

    // cohort-localized XCD swizzle (bijective: 8 XCD x 3 phases x 4 mb x 8 nb)
    const int bid = blockIdx.x;
    const int xcd = bid & 7;
    const int l = bid >> 3;                    // 0..95
    const int mb = xcd * 4 + ((l >> 3) & 3);   // 0..31
    const int nb = ((l >> 5) << 3) + (l & 7);  // 0..23
    const int m0 = mb << 8;
    const int n0 = nb << 8;

    // staging constants: chunk = q*512 + tid -> row, swizzled k-chunk
    int s_row[2], s_kc[2];
#pragma unroll
    for (int q_ = 0; q_ < 2; ++q_) {
        const int chunk = q_ * 512 + tid;
        const int r_ = chunk >> 3;
        const int c_ = chunk & 7;
        s_row[q_] = r_;
        s_kc[q_] = (c_ ^ (r_ & 7)) * 8;  // element offset
    }

    f32x4 acc[8][4] = {};
    bf16x8 aF[2][4];
    bf16x8 bF0[2][2];
    bf16x8 bF1[2][2];

    // prologue (14 loads, FIFO oldest->newest):
    // s4(2),s0(2),s5(2),s1(2),s6(2),s2(2),s7(2)
    STAGE_B(4, 0, 0); STAGE_A(0, 0, 0); STAGE_B(5, 0, 1);
    STAGE_A(1, 0, 1); STAGE_B(6, 1, 0);
    STAGE_A(2, 1, 0); STAGE_B(7, 1, 1);
    WC8;  // completes s4,s0,s5 (loads 1-6); leaves {s1,s6,s2,s7} = invariant
    __builtin_amdgcn_s_barrier();
    RD_B(bF0, 0, 0);  // pre-read B(0,h0) from s4 (complete)
    asm volatile("s_waitcnt lgkmcnt(0)" ::: "memory");
    __builtin_amdgcn_s_barrier();  // s4 safe to re-stage from Q1 on

    // 64 K-tiles, 2 per iteration; i=31 is the peeled tail
    for (int i = 0; i < 31; ++i) {
        const int t0 = 2 * i;
        const int t1 = t0 + 1, t2 = t0 + 2, t3 = t0 + 3;
        PH4(RD_A(t0, 0); RD_B(bF1, t0, 1),
            STAGE_A(3, t1, 1); STAGE_B(4, t2, 0),
            MM(0, 0, bF0); MM(0, 1, bF1), ;, ;, WC8);
        PH4(RD_A(t0, 1),
            STAGE_A(0, t2, 0); STAGE_B(5, t2, 1),
            MM(1, 0, bF0), RD_B(bF0, t1, 0), MM(1, 1, bF1), WC8);
        PH4(RD_A(t1, 0); RD_B(bF1, t1, 1),
            STAGE_A(1, t2, 1); STAGE_B(6, t3, 0),
            MM(0, 0, bF0); MM(0, 1, bF1), ;, ;, WC8);
        PH4(RD_A(t1, 1),
            STAGE_A(2, t3, 0); STAGE_B(7, t3, 1),
            MM(1, 0, bF0), RD_B(bF0, t2, 0), MM(1, 1, bF1), WC8);
    }
    // tail: t0=62, t1=63. Entering outstanding = {s1,s6(Q3), s2,s7(Q4)} = 8.
    // T1 rd s0,s5 (completed by loop Q4 WC8); stage s3 (+2 -> 10);
    //    WC6 completes s1,s6 (for T2); leaves {s2,s7,s3}.
    // T2 rd s1,s6; WC2 completes s2,s7 (for T3); leaves {s3}.
    // T3 rd s2,s7; WC0 completes s3 (for T4).
    // T4 rd s3.
    PH4(RD_A(62, 0); RD_B(bF1, 62, 1),
        STAGE_A(3, 63, 1),
        MM(0, 0, bF0); MM(0, 1, bF1), ;, ;, WC6);
    PH4(RD_A(62, 1), ;,
        MM(1, 0, bF0), RD_B(bF0, 63, 0), MM(1, 1, bF1), WC2);
    PH4(RD_A(63, 0); RD_B(bF1, 63, 1), ;,
        MM(0, 0, bF0); MM(0, 1, bF1), ;, ;, WC0);
    PH4(RD_A(63, 1), ;,
        MM(1, 0, bF0), ;, MM(1, 1, bF1), );

    // C-write: D layout col = lane&15, row = (lane>>4)*4 + j
#pragma unroll
    for (int mf = 0; mf < 8; ++mf) {
#pragma unroll
        for (int nf = 0; nf < 4; ++nf) {
            const int n = n0 + wn * 64 + nf * 16 + fr;
            const int64_t mbase = (int64_t)(m0 + wm * 128 + mf * 16 + kg * 4);
#pragma unroll
            for (int j = 0; j < 4; ++j) {
                G[(mbase + j) * NDIM + n] = f2bf(acc[mf][nf][j]);
            }
        }
    }
}

// ---------------- LSTM elementwise epilogue (plain vectorized I/O) -------

__global__ void lstm_epi_kernel(const uint16_t* __restrict__ G,
                                const float* __restrict__ c_prev,
                                const float* __restrict__ b_f,
                                const float* __restrict__ b_o,
                                const float* __restrict__ b_c,
                                float* __restrict__ h_out,
                                float* __restrict__ c_out) {
    const int64_t total = (int64_t)BDIM * HDIM / 8;
    for (int64_t i = (int64_t)blockIdx.x * blockDim.x + threadIdx.x; i < total;
         i += (int64_t)gridDim.x * blockDim.x) {
        const int64_t e = i << 3;
        const int m = (int)(e >> 11);
        const int n = (int)(e & 2047);
        const int64_t gb = (int64_t)m * NDIM + n;
        const short8 fv = *(const short8*)(G + gb);
        const short8 ov = *(const short8*)(G + gb + HDIM);
        const short8 cv = *(const short8*)(G + gb + 2 * HDIM);
        const f32x4 cp0 = *(const f32x4*)(c_prev + (int64_t)m * HDIM + n);
        const f32x4 cp1 = *(const f32x4*)(c_prev + (int64_t)m * HDIM + n + 4);
        float cp[8] = {cp0[0], cp0[1], cp0[2], cp0[3], cp1[0], cp1[1], cp1[2], cp1[3]};
        float hr[8], cr[8];
#pragma unroll
        for (int j = 0; j < 8; ++j) {
            const float fpre = bf2f((uint16_t)fv[j]) + b_f[n + j];
            const float opre = bf2f((uint16_t)ov[j]) + b_o[n + j];
            const float cpre = bf2f((uint16_t)cv[j]) + b_c[n + j];
            const float ft = fast_sigmoid(fpre);
            const float ot = fast_sigmoid(opre);
            const float ch = fast_tanh(cpre);
            const float ct = ft * cp[j] + (1.0f - ft) * ch;
            hr[j] = ot * fast_tanh(ct);
            cr[j] = ct;
        }
        f32x4 h0 = {hr[0], hr[1], hr[2], hr[3]};
        f32x4 h1 = {hr[4], hr[5], hr[6], hr[7]};
        f32x4 c0 = {cr[0], cr[1], cr[2], cr[3]};
        f32x4 c1 = {cr[4], cr[5], cr[6], cr[7]};
        *(f32x4*)(h_out + (int64_t)m * HDIM + n) = h0;
        *(f32x4*)(h_out + (int64_t)m * HDIM + n + 4) = h1;
        *(f32x4*)(c_out + (int64_t)m * HDIM + n) = c0;
        *(f32x4*)(c_out + (int64_t)m * HDIM + n + 4) = c1;
    }
}

extern "C" void kernel_launch(void* const* d_in, const int* in_sizes, int n_in,
                              void* d_out, int out_size, void* d_ws, size_t ws_size,
                              hipStream_t stream) {
    const float* x_t   = (const float*)d_in[0];
    const float* h_t_1 = (const float*)d_in[1];
    const float* c_t_1 = (const float*)d_in[2];
    const float* W_f   = (const float*)d_in[3];
    const float* b_f   = (const float*)d_in[4];
    const float* W_o   = (const float*)d_in[5];
    const float* b_o   = (const float*)d_in[6];
    const float* W_c   = (const float*)d_in[7];
    const float* b_c   = (const float*)d_in[8];

    uint16_t* xh  = (uint16_t*)d_ws;                            // 64 MiB
    uint16_t* Wbf = xh + (size_t)BDIM * KDIM;                   // 48 MiB
    uint16_t* G   = Wbf + (size_t)NDIM * KDIM;                  // 96 MiB

    float* h_out = (float*)d_out;
    float* c_out = h_out + (size_t)BDIM * HDIM;

    cvt_all_kernel<<<2048, 256, 0, stream>>>(x_t, h_t_1, W_f, W_o, W_c, xh, Wbf);
    lstm_gemm4p_kernel<<<768, 512, 0, stream>>>(xh, Wbf, G);
    lstm_epi_kernel<<<2048, 256, 0, stream>>>(G, c_t_1, b_f, b_o, b_c,
                                              h_out, c_out);
}